// Round 14
// baseline (197.294 us; speedup 1.0000x reference)
//
#include <hip/hip_runtime.h>
#include <stdint.h>

#define TOK   8192
#define DIM   1024
#define NEXP  8
#define TOPK  2
#define WPAD  1028

typedef unsigned short ushort_t;
typedef __attribute__((ext_vector_type(8))) short bf16x8;
typedef __attribute__((ext_vector_type(4))) float f32x4;

__device__ __forceinline__ unsigned short f2bf(float f) {
  unsigned int u = __float_as_uint(f);
  u += 0x7fffu + ((u >> 16) & 1u);
  return (unsigned short)(u >> 16);
}
__device__ __forceinline__ float bf2f(ushort_t u) {
  return __uint_as_float(((unsigned int)u) << 16);
}

__device__ __forceinline__ void gload_lds16(const void* g, void* l) {
  __builtin_amdgcn_global_load_lds(
      (const __attribute__((address_space(1))) void*)(uintptr_t)g,
      (__attribute__((address_space(3))) void*)(unsigned int)(uintptr_t)l,
      16, 0, 0);
}

// ---- merged prep: router+cast (blocks 0..511) | transpose (512..1471) ----
__global__ __launch_bounds__(256) void k_prep(
    const float* __restrict__ x, const float* __restrict__ Wg,
    ushort_t* __restrict__ xb, int* __restrict__ tid, float* __restrict__ tw,
    const float* __restrict__ sg, const float* __restrict__ su,
    const float* __restrict__ sd, const float* __restrict__ wgm,
    const float* __restrict__ wu, const float* __restrict__ wdn,
    ushort_t* __restrict__ Wsh1, ushort_t* __restrict__ Wsd,
    ushort_t* __restrict__ Wgu, ushort_t* __restrict__ Wd) {
  __shared__ float sm[2 * 64 * 65];
  if (blockIdx.x < 512) {
    for (int j = threadIdx.x; j < DIM * NEXP; j += 256)
      sm[(j & 7) * WPAD + (j >> 3)] = Wg[j];
    __syncthreads();
    const int wid = threadIdx.x >> 6, lane = threadIdx.x & 63;
#pragma unroll
    for (int tt2 = 0; tt2 < 4; ++tt2) {
      const int t = blockIdx.x * 16 + wid * 4 + tt2;
      const float* xr = x + (size_t)t * DIM;
      ushort_t* xw = xb + (size_t)t * DIM;
      float acc[NEXP];
#pragma unroll
      for (int e = 0; e < NEXP; ++e) acc[e] = 0.f;
#pragma unroll
      for (int k = 0; k < 4; ++k) {
        const int i = k * 256 + lane * 4;
        const float4 xv = *(const float4*)(xr + i);
        union { ushort_t u[4]; uint2 v; } s;
        s.u[0] = f2bf(xv.x); s.u[1] = f2bf(xv.y);
        s.u[2] = f2bf(xv.z); s.u[3] = f2bf(xv.w);
        *(uint2*)(xw + i) = s.v;
#pragma unroll
        for (int e = 0; e < NEXP; ++e) {
          const float4 wv = *(const float4*)&sm[e * WPAD + i];
          acc[e] += xv.x * wv.x + xv.y * wv.y + xv.z * wv.z + xv.w * wv.w;
        }
      }
#pragma unroll
      for (int e = 0; e < NEXP; ++e) {
        float v = acc[e];
#pragma unroll
        for (int o = 32; o > 0; o >>= 1) v += __shfl_xor(v, o);
        acc[e] = v;
      }
      if (lane == 0) {
        float mx = acc[0];
#pragma unroll
        for (int e = 1; e < NEXP; ++e) mx = fmaxf(mx, acc[e]);
        float p[NEXP]; float s = 0.f;
#pragma unroll
        for (int e = 0; e < NEXP; ++e) { p[e] = __expf(acc[e] - mx); s += p[e]; }
        const float inv = 1.f / s;
#pragma unroll
        for (int e = 0; e < NEXP; ++e) p[e] *= inv;
        int i1 = 0; float s1 = p[0];
#pragma unroll
        for (int e = 1; e < NEXP; ++e) if (p[e] > s1) { s1 = p[e]; i1 = e; }
        int i2 = -1; float s2 = -1.f;
#pragma unroll
        for (int e = 0; e < NEXP; ++e) if (e != i1 && p[e] > s2) { s2 = p[e]; i2 = e; }
        tid[t * 2] = i1; tid[t * 2 + 1] = i2;
        tw[t * 2] = s1;  tw[t * 2 + 1] = s2;
      }
    }
    return;
  }
  int b = blockIdx.x - 512;
  const float *s0, *s1; ushort_t* dst; int R, C; bool ilv;
  int r0, c0;
  if (b < 128) {
    ilv = true; s0 = sg; s1 = su; dst = Wsh1; R = 1024; C = 512;
    c0 = (b & 7) * 64; r0 = (b >> 3) * 64;
  } else if (b < 640) {
    b -= 128; const int e = b >> 6; b &= 63;
    ilv = true;
    s0 = wgm + (size_t)e * 1024 * 256; s1 = wu + (size_t)e * 1024 * 256;
    dst = Wgu + (size_t)e * 512 * 1024; R = 1024; C = 256;
    c0 = (b & 3) * 64; r0 = (b >> 2) * 64;
  } else if (b < 704) {
    b -= 640; ilv = false; s0 = sd; s1 = sd; dst = Wsd; R = 512; C = 1024;
    c0 = (b & 7) * 128; r0 = (b >> 3) * 64;
  } else {
    b -= 704; const int e = b >> 5; b &= 31;
    ilv = false;
    s0 = wdn + (size_t)e * 256 * 1024; s1 = s0;
    dst = Wd + (size_t)e * 1024 * 256; R = 256; C = 1024;
    c0 = (b & 7) * 128; r0 = (b >> 3) * 64;
  }
  const int row16 = threadIdx.x >> 4;
  const int q16   = threadIdx.x & 15;
#pragma unroll
  for (int p = 0; p < 2; ++p) {
    const float* s = p ? s1 : s0;
    const int cc = ilv ? c0 : (c0 + p * 64);
    float (*tt)[65] = (float(*)[65])(sm + p * 64 * 65);
#pragma unroll
    for (int i = 0; i < 64; i += 16) {
      const float4 v = *(const float4*)&s[(size_t)(r0 + row16 + i) * C + cc + q16 * 4];
      tt[q16 * 4 + 0][row16 + i] = v.x;
      tt[q16 * 4 + 1][row16 + i] = v.y;
      tt[q16 * 4 + 2][row16 + i] = v.z;
      tt[q16 * 4 + 3][row16 + i] = v.w;
    }
  }
  __syncthreads();
#pragma unroll
  for (int p = 0; p < 2; ++p) {
    const int cc = ilv ? c0 : (c0 + p * 64);
    float (*tt)[65] = (float(*)[65])(sm + p * 64 * 65);
#pragma unroll
    for (int i = 0; i < 64; i += 16) {
      const int n = cc + row16 + i;
      const int drow = ilv ? (2 * n + p) : n;
      const float4 v = *(const float4*)&tt[row16 + i][q16 * 4];
      union { ushort_t u[4]; uint2 w; } s4;
      s4.u[0] = f2bf(v.x); s4.u[1] = f2bf(v.y);
      s4.u[2] = f2bf(v.z); s4.u[3] = f2bf(v.w);
      *(uint2*)&dst[(size_t)drow * R + r0 + q16 * 4] = s4.w;
    }
  }
}

// ---------------- histogram + prefix ----------------
__global__ __launch_bounds__(1024) void k_scan(const int* __restrict__ tid,
                                               int* __restrict__ cnt,
                                               int* __restrict__ off,
                                               int* __restrict__ cnt2) {
  __shared__ int h[NEXP];
  if (threadIdx.x < NEXP) h[threadIdx.x] = 0;
  __syncthreads();
  int loc[NEXP];
#pragma unroll
  for (int e = 0; e < NEXP; ++e) loc[e] = 0;
  const int4* t4 = (const int4*)tid;
#pragma unroll
  for (int k = 0; k < TOK * TOPK / 4 / 1024; ++k) {
    const int4 v = t4[threadIdx.x + k * 1024];
#pragma unroll
    for (int e = 0; e < NEXP; ++e)
      loc[e] += (v.x == e) + (v.y == e) + (v.z == e) + (v.w == e);
  }
#pragma unroll
  for (int e = 0; e < NEXP; ++e) if (loc[e]) atomicAdd(&h[e], loc[e]);
  __syncthreads();
  if (threadIdx.x == 0) {
    int run = 0;
    for (int e = 0; e < NEXP; ++e) { off[e] = run; cnt[e] = h[e]; run += h[e]; }
  }
  if (threadIdx.x < NEXP) cnt2[threadIdx.x] = 0;
}

// ---------------- ballot-ranked scatter ----------------
__global__ __launch_bounds__(256) void k_scatter(const int* __restrict__ tid,
                                                 const float* __restrict__ tw,
                                                 const int* __restrict__ off,
                                                 int* __restrict__ cnt2,
                                                 int* __restrict__ tok,
                                                 float* __restrict__ wgt,
                                                 int* __restrict__ dstrow) {
  const int t = blockIdx.x * 256 + threadIdx.x;
  const int lane = threadIdx.x & 63;
#pragma unroll
  for (int j = 0; j < TOPK; ++j) {
    const int e = tid[t * 2 + j];
    const float w = tw[t * 2 + j];
    int slot = 0;
#pragma unroll
    for (int ee = 0; ee < NEXP; ++ee) {
      const unsigned long long m = __ballot(e == ee);
      if (m) {
        const int r = __popcll(m & ((1ull << lane) - 1ull));
        const int leader = __ffsll((unsigned long long)m) - 1;
        int base = 0;
        if (lane == leader) base = atomicAdd(&cnt2[ee], (int)__popcll(m));
        base = __shfl(base, leader);
        if (e == ee) slot = off[ee] + base + r;
      }
    }
    tok[slot] = t;
    wgt[slot] = w;
    dstrow[slot] = t * 2 + j;
  }
}

// ---- GEMM1: 256x256, BK=32, 4-buffer ring, never-drain vmcnt(8) ------------
// 256 blocks x 512 thr (8 waves, 2M x 4N; wave tile 128x64).
// wg<128: routed expert e=wg>>4 (gather via tok, B=Wgu[e], N=512 -> he);
// wg>=128: shared (A=xb, B=Wsh1, N=1024 -> hs). LDS 4 bufs x (16+16)KB = 128KB.
__global__ __launch_bounds__(512, 1) void k_gemm1(
    const ushort_t* __restrict__ A0, const ushort_t* __restrict__ Bgu,
    const ushort_t* __restrict__ Bsh,
    ushort_t* __restrict__ he, ushort_t* __restrict__ hs,
    const int* __restrict__ tok,
    const int* __restrict__ cnt, const int* __restrict__ off) {
  constexpr int K = 1024, NT = 32;               // 32 K-tiles of 32
  __shared__ __attribute__((aligned(16))) ushort_t lA[4][256 * 32];
  __shared__ __attribute__((aligned(16))) ushort_t lB[4][256 * 32];

  const int wg = (blockIdx.x & 7) * 32 + (blockIdx.x >> 3);
  int mbslot, nb, MB, m_e, offE = 0;
  bool gat;
  const ushort_t* Bblk;
  if (wg < 128) {
    const int g = wg >> 4;
    const int r = wg & 15;
    mbslot = r >> 1; nb = r & 1; MB = 8;
    gat = true; m_e = cnt[g]; offE = off[g];
    Bblk = Bgu + (size_t)g * 512 * 1024;
  } else {
    const int r = wg - 128;
    mbslot = r >> 2; nb = r & 3; MB = 32;
    gat = false; m_e = TOK;
    Bblk = Bsh;
  }
  if (m_e == 0) return;
  const int nBase = nb * 256;

  const int wid = threadIdx.x >> 6, lane = threadIdx.x & 63;
  const int wm = wid >> 2, wn = wid & 3;
  const int l15 = lane & 15, lq = lane >> 4;

  // staging geometry: slot sl = (c*8+wid)*64 + lane, c in {0,1};
  // row = sl>>2 (4 x 16B slots per 32-elem row), s = sl&3,
  // swizzled source col-slot = s ^ ((row>>1)&3).
  int srow[2], scol[2];
  const ushort_t* bsrc[2];
#pragma unroll
  for (int c = 0; c < 2; ++c) {
    const int sl = (c * 8 + wid) * 64 + lane;
    srow[c] = sl >> 2;
    scol[c] = (sl & 3) ^ ((srow[c] >> 1) & 3);
    bsrc[c] = Bblk + (size_t)(nBase + srow[c]) * K + scol[c] * 8;
  }

  for (int mb = mbslot; mb * 256 < m_e; mb += MB) {
    const int mBase = mb * 256;
    const ushort_t* asrc[2];
#pragma unroll
    for (int c = 0; c < 2; ++c) {
      const int gr = mBase + srow[c];
      const int gc = (gr < m_e) ? gr : (m_e - 1);
      const ushort_t* ar = gat ? (A0 + (size_t)tok[offE + gc] * 1024)
                               : (A0 + (size_t)gc * K);
      asrc[c] = ar + scol[c] * 8;
    }

    auto stage = [&](int buf, int kt) {
#pragma unroll
      for (int c = 0; c < 2; ++c) {
        gload_lds16(asrc[c] + kt, &lA[buf][(c * 8 + wid) * 512]);
        gload_lds16(bsrc[c] + kt, &lB[buf][(c * 8 + wid) * 512]);
      }
    };

    f32x4 acc[8][4];
#pragma unroll
    for (int mi = 0; mi < 8; ++mi)
#pragma unroll
      for (int ni = 0; ni < 4; ++ni) acc[mi][ni] = (f32x4){0.f, 0.f, 0.f, 0.f};

    stage(0, 0); stage(1, 32); stage(2, 64);     // 12 loads in flight
    for (int t = 0; t < NT; ++t) {
      if (t + 2 < NT)      asm volatile("s_waitcnt vmcnt(8)" ::: "memory");
      else if (t + 1 < NT) asm volatile("s_waitcnt vmcnt(4)" ::: "memory");
      else                 asm volatile("s_waitcnt vmcnt(0)" ::: "memory");
      __builtin_amdgcn_s_barrier();
      if (t + 3 < NT) stage((t + 3) & 3, (t + 3) * 32);  // after barrier: safe

      const char* sA = (const char*)lA[t & 3];
      const char* sB = (const char*)lB[t & 3];
      bf16x8 af[8], bfr[4];
#pragma unroll
      for (int ni = 0; ni < 4; ++ni) {
        const int row = wn * 64 + ni * 16 + l15;
        bfr[ni] = *(const bf16x8*)(sB + row * 64 + ((lq ^ ((row >> 1) & 3)) << 4));
      }
#pragma unroll
      for (int mi = 0; mi < 8; ++mi) {
        const int row = wm * 128 + mi * 16 + l15;
        af[mi] = *(const bf16x8*)(sA + row * 64 + ((lq ^ ((row >> 1) & 3)) << 4));
      }
      __builtin_amdgcn_s_setprio(1);
#pragma unroll
      for (int mi = 0; mi < 8; ++mi)
#pragma unroll
        for (int ni = 0; ni < 4; ++ni)
          acc[mi][ni] = __builtin_amdgcn_mfma_f32_16x16x32_bf16(
              af[mi], bfr[ni], acc[mi][ni], 0, 0, 0);
      __builtin_amdgcn_s_setprio(0);
    }
    __builtin_amdgcn_s_barrier();   // close reads before next m-tile restages

    // epilogue: SwiGLU (even col = gate, odd = up)
#pragma unroll
    for (int mi = 0; mi < 8; ++mi) {
#pragma unroll
      for (int r = 0; r < 4; ++r) {
        const int gg = mBase + wm * 128 + mi * 16 + lq * 4 + r;
        const bool ok = gg < m_e;
#pragma unroll
        for (int ni = 0; ni < 4; ++ni) {
          const float v = acc[mi][ni][r];
          const int c = nBase + wn * 64 + ni * 16 + l15;
          const float o = __shfl_xor(v, 1);
          if (!(c & 1) && ok) {
            const float hv = (v / (1.f + __expf(-v))) * o;
            if (gat) he[(size_t)(offE + gg) * 256 + (c >> 1)] = f2bf(hv);
            else     hs[(size_t)gg * 512 + (c >> 1)] = f2bf(hv);
          }
        }
      }
    }
  }
}

// ---------------- GEMM2r: routed, B-resident strip, streaming A -------------
__global__ __launch_bounds__(512, 1) void k_gemm2r(
    const ushort_t* __restrict__ he, const ushort_t* __restrict__ Wd,
    ushort_t* __restrict__ contrib, const float* __restrict__ wgt,
    const int* __restrict__ cnt, const int* __restrict__ off,
    const int* __restrict__ dstrow) {
  constexpr int K = 256;
  __shared__ __attribute__((aligned(16))) ushort_t lB[128 * 256];
  __shared__ __attribute__((aligned(16))) ushort_t lA[2][256 * 64];

  const int wg = (blockIdx.x & 7) * 32 + (blockIdx.x >> 3);
  const int e = wg >> 5;
  const int r = wg & 31;
  const int nb = r >> 2;
  const int mslot = r & 3;
  const int nBase = nb * 128;

  const int m_e = cnt[e];
  if (m_e == 0) return;
  const int offE = off[e];
  const ushort_t* Abase = he + (size_t)offE * K;
  const ushort_t* Bblk = Wd + (size_t)e * 1024 * K;

  const int wid = threadIdx.x >> 6, lane = threadIdx.x & 63;
  const int wm = wid >> 1, wn = wid & 1;
  const int l15 = lane & 15, lq = lane >> 4;

#pragma unroll
  for (int i = 0; i < 8; ++i) {
    const int sl = (wid * 8 + i) * 64 + lane;
    const int row = sl >> 5;
    const int s = sl & 31;
    const int c = (s & ~7) | ((s & 7) ^ (row & 7));
    gload_lds16(Bblk + (size_t)(nBase + row) * K + c * 8,
                ((char*)lB) + (size_t)(wid * 8 + i) * 1024);
  }

  auto stageA = [&](int buf, int mBase, int h) {
#pragma unroll
    for (int i = 0; i < 4; ++i) {
      const int sl = (wid * 4 + i) * 64 + lane;
      const int row = sl >> 3;
      const int s = sl & 7;
      const int c = s ^ (row & 7);
      const int gr = mBase + row;
      const int gc = (gr < m_e) ? gr : (m_e - 1);
      gload_lds16(Abase + (size_t)gc * K + h * 64 + c * 8,
                  ((char*)lA) + buf * 32768 + (size_t)(wid * 4 + i) * 1024);
    }
  };

  stageA(0, mslot * 256, 0);
  int cur = 0;
  for (int tm = mslot; tm * 256 < m_e; tm += 4) {
    const int mBase = tm * 256;
    f32x4 acc[4][4];
#pragma unroll
    for (int mi = 0; mi < 4; ++mi)
#pragma unroll
      for (int ni = 0; ni < 4; ++ni) acc[mi][ni] = (f32x4){0.f, 0.f, 0.f, 0.f};

    for (int h = 0; h < 4; ++h) {
      int nh = h + 1, ntm = tm;
      if (nh == 4) { nh = 0; ntm = tm + 4; }
      const bool has_next = (ntm * 256 < m_e);
      if (has_next) {
        stageA(cur ^ 1, ntm * 256, nh);
        asm volatile("s_waitcnt vmcnt(4)" ::: "memory");
      } else {
        asm volatile("s_waitcnt vmcnt(0)" ::: "memory");
      }
      __builtin_amdgcn_s_barrier();
      const char* sA = (const char*)lA + cur * 32768;
#pragma unroll
      for (int kk = 0; kk < 2; ++kk) {
        bf16x8 af[4], bfr[4];
#pragma unroll
        for (int mi = 0; mi < 4; ++mi) {
          const int row = wm * 64 + mi * 16 + l15;
          const int cb = ((kk * 4 + lq) ^ (row & 7)) << 4;
          af[mi] = *(const bf16x8*)(sA + row * 128 + cb);
        }
#pragma unroll
        for (int ni = 0; ni < 4; ++ni) {
          const int brow = wn * 64 + ni * 16 + l15;
          const int ck = h * 8 + kk * 4 + lq;
          const int s = (ck & ~7) | ((ck & 7) ^ (brow & 7));
          bfr[ni] = *(const bf16x8*)((const char*)lB + brow * 512 + s * 16);
        }
#pragma unroll
        for (int mi = 0; mi < 4; ++mi)
#pragma unroll
          for (int ni = 0; ni < 4; ++ni)
            acc[mi][ni] = __builtin_amdgcn_mfma_f32_16x16x32_bf16(
                af[mi], bfr[ni], acc[mi][ni], 0, 0, 0);
      }
      __builtin_amdgcn_s_barrier();
      cur ^= 1;
    }

#pragma unroll
    for (int mi = 0; mi < 4; ++mi) {
#pragma unroll
      for (int rr = 0; rr < 4; ++rr) {
        const int gg = mBase + wm * 64 + mi * 16 + lq * 4 + rr;
        if (gg < m_e) {
          const float w = wgt[offE + gg];
          const int dr = dstrow[offE + gg];
#pragma unroll
          for (int ni = 0; ni < 4; ++ni) {
            const int c = nBase + wn * 64 + ni * 16 + l15;
            contrib[(size_t)dr * 1024 + c] = f2bf(acc[mi][ni][rr] * w);
          }
        }
      }
    }
  }
  asm volatile("s_waitcnt vmcnt(0)" ::: "memory");
}

// ---------------- GEMM2s: shared + combine ----------------
__global__ __launch_bounds__(512, 1) void k_gemm2s(
    const ushort_t* __restrict__ hs, const ushort_t* __restrict__ Wsd,
    const ushort_t* __restrict__ contrib, float* __restrict__ out) {
  constexpr int K = 512;
  __shared__ __attribute__((aligned(16))) ushort_t lB[64 * 512];
  __shared__ __attribute__((aligned(16))) ushort_t lA[2][256 * 64];

  const int wg = (blockIdx.x & 7) * 32 + (blockIdx.x >> 3);
  const int nstrip = wg >> 4;
  const int mslot = wg & 15;
  const int nBase = nstrip * 64;

  const int wid = threadIdx.x >> 6, lane = threadIdx.x & 63;
  const int wm = wid >> 1, wn = wid & 1;
  const int l15 = lane & 15, lq = lane >> 4;

#pragma unroll
  for (int i = 0; i < 8; ++i) {
    const int sl = (wid * 8 + i) * 64 + lane;
    const int row = sl >> 6;
    const int s = sl & 63;
    const int c = (s & ~7) | ((s & 7) ^ (row & 7));
    gload_lds16(Wsd + (size_t)(nBase + row) * K + c * 8,
                ((char*)lB) + (size_t)(wid * 8 + i) * 1024);
  }

  auto stageA = [&](int buf, int mBase, int h) {
#pragma unroll
    for (int i = 0; i < 4; ++i) {
      const int sl = (wid * 4 + i) * 64 + lane;
      const int row = sl >> 3;
      const int s = sl & 7;
      const int c = s ^ (row & 7);
      gload_lds16(hs + (size_t)(mBase + row) * K + h * 64 + c * 8,
                  ((char*)lA) + buf * 32768 + (size_t)(wid * 4 + i) * 1024);
    }
  };

  stageA(0, mslot * 256, 0);
  int cur = 0;
  for (int tm = mslot; tm * 256 < TOK; tm += 16) {
    const int mBase = tm * 256;
    f32x4 acc[4][2];
#pragma unroll
    for (int mi = 0; mi < 4; ++mi)
#pragma unroll
      for (int ni = 0; ni < 2; ++ni) acc[mi][ni] = (f32x4){0.f, 0.f, 0.f, 0.f};

    for (int h = 0; h < 8; ++h) {
      int nh = h + 1, ntm = tm;
      if (nh == 8) { nh = 0; ntm = tm + 16; }
      const bool has_next = (ntm * 256 < TOK);
      if (has_next) {
        stageA(cur ^ 1, ntm * 256, nh);
        asm volatile("s_waitcnt vmcnt(4)" ::: "memory");
      } else {
        asm volatile("s_waitcnt vmcnt(0)" ::: "memory");
      }
      __builtin_amdgcn_s_barrier();
      const char* sA = (const char*)lA + cur * 32768;
#pragma unroll
      for (int kk = 0; kk < 2; ++kk) {
        bf16x8 af[4], bfr[2];
#pragma unroll
        for (int mi = 0; mi < 4; ++mi) {
          const int row = wm * 64 + mi * 16 + l15;
          const int cb = ((kk * 4 + lq) ^ (row & 7)) << 4;
          af[mi] = *(const bf16x8*)(sA + row * 128 + cb);
        }
#pragma unroll
        for (int ni = 0; ni < 2; ++ni) {
          const int brow = wn * 32 + ni * 16 + l15;
          const int ck = h * 8 + kk * 4 + lq;
          const int s = (ck & ~7) | ((ck & 7) ^ (brow & 7));
          bfr[ni] = *(const bf16x8*)((const char*)lB + brow * 1024 + s * 16);
        }
#pragma unroll
        for (int mi = 0; mi < 4; ++mi)
#pragma unroll
          for (int ni = 0; ni < 2; ++ni)
            acc[mi][ni] = __builtin_amdgcn_mfma_f32_16x16x32_bf16(
                af[mi], bfr[ni], acc[mi][ni], 0, 0, 0);
      }
      __builtin_amdgcn_s_barrier();
      cur ^= 1;
    }

#pragma unroll
    for (int mi = 0; mi < 4; ++mi) {
#pragma unroll
      for (int rr = 0; rr < 4; ++rr) {
        const int gg = mBase + wm * 64 + mi * 16 + lq * 4 + rr;
#pragma unroll
        for (int ni = 0; ni < 2; ++ni) {
          const int c = nBase + wn * 32 + ni * 16 + l15;
          out[(size_t)gg * 1024 + c] = acc[mi][ni][rr]
              + bf2f(contrib[(size_t)(gg * 2) * 1024 + c])
              + bf2f(contrib[(size_t)(gg * 2 + 1) * 1024 + c]);
        }
      }
    }
  }
  asm volatile("s_waitcnt vmcnt(0)" ::: "memory");
}

// ---------------- launch ----------------
extern "C" void kernel_launch(void* const* d_in, const int* in_sizes, int n_in,
                              void* d_out, int out_size, void* d_ws, size_t ws_size,
                              hipStream_t stream) {
  (void)in_sizes; (void)n_in; (void)out_size; (void)ws_size;
  const float* x      = (const float*)d_in[0];
  const float* Wg     = (const float*)d_in[1];
  const float* w_gate = (const float*)d_in[2];
  const float* w_up   = (const float*)d_in[3];
  const float* w_down = (const float*)d_in[4];
  const float* sg     = (const float*)d_in[5];
  const float* su     = (const float*)d_in[6];
  const float* sd     = (const float*)d_in[7];
  float* out = (float*)d_out;

  char* ws = (char*)d_ws;
  size_t o = 0;
  ushort_t* xb    = (ushort_t*)(ws + o); o += (size_t)TOK * DIM * 2;
  ushort_t* Wsh1  = (ushort_t*)(ws + o); o += (size_t)1024 * 1024 * 2;
  ushort_t* Wsd   = (ushort_t*)(ws + o); o += (size_t)1024 * 512 * 2;
  ushort_t* Wgu   = (ushort_t*)(ws + o); o += (size_t)NEXP * 512 * 1024 * 2;
  ushort_t* Wd    = (ushort_t*)(ws + o); o += (size_t)NEXP * 1024 * 256 * 2;
  ushort_t* hs    = (ushort_t*)(ws + o); o += (size_t)TOK * 512 * 2;
  ushort_t* he    = (ushort_t*)(ws + o); o += (size_t)TOK * TOPK * 256 * 2;
  int*   tid   = (int*)(ws + o);   o += (size_t)TOK * TOPK * 4;
  float* tw    = (float*)(ws + o); o += (size_t)TOK * TOPK * 4;
  int*   tok   = (int*)(ws + o);   o += (size_t)TOK * TOPK * 4;
  float* wgt   = (float*)(ws + o); o += (size_t)TOK * TOPK * 4;
  int*   dstrow= (int*)(ws + o);   o += (size_t)TOK * TOPK * 4;
  int*   cnt   = (int*)(ws + o);   o += 64;
  int*   offp  = (int*)(ws + o);   o += 64;
  int*   cnt2  = (int*)(ws + o);   o += 64;
  ushort_t* contrib = (ushort_t*)(ws + o);  // [TOK*2][1024] bf16, token-major

  k_prep<<<1472, 256, 0, stream>>>(x, Wg, xb, tid, tw, sg, su, sd,
                                   w_gate, w_up, w_down, Wsh1, Wsd, Wgu, Wd);
  k_scan<<<1, 1024, 0, stream>>>(tid, cnt, offp, cnt2);
  k_scatter<<<TOK / 256, 256, 0, stream>>>(tid, tw, offp, cnt2, tok, wgt, dstrow);

  // merged GEMM1 (routed gathered + shared), 256 blocks x 512 thr, 4-buf ring
  k_gemm1<<<256, 512, 0, stream>>>(xb, Wgu, Wsh1, he, hs, tok, cnt, offp);
  // routed GEMM2 -> token-major bf16 contrib
  k_gemm2r<<<256, 512, 0, stream>>>(he, Wd, contrib, wgt, cnt, offp, dstrow);
  // shared GEMM2 + combine -> out
  k_gemm2s<<<256, 512, 0, stream>>>(hs, Wsd, contrib, out);
}

// Round 15
// 171.400 us; speedup vs baseline: 1.1511x; 1.1511x over previous
//
#include <hip/hip_runtime.h>
#include <stdint.h>

#define TOK   8192
#define DIM   1024
#define NEXP  8
#define TOPK  2
#define WPAD  1028

typedef unsigned short ushort_t;
typedef __attribute__((ext_vector_type(8))) short bf16x8;
typedef __attribute__((ext_vector_type(4))) float f32x4;

__device__ __forceinline__ unsigned short f2bf(float f) {
  unsigned int u = __float_as_uint(f);
  u += 0x7fffu + ((u >> 16) & 1u);
  return (unsigned short)(u >> 16);
}
__device__ __forceinline__ float bf2f(ushort_t u) {
  return __uint_as_float(((unsigned int)u) << 16);
}

__device__ __forceinline__ void gload_lds16(const void* g, void* l) {
  __builtin_amdgcn_global_load_lds(
      (const __attribute__((address_space(1))) void*)(uintptr_t)g,
      (__attribute__((address_space(3))) void*)(unsigned int)(uintptr_t)l,
      16, 0, 0);
}

// ---- merged prep: router+cast (blocks 0..511) | transpose (512..1471) ----
__global__ __launch_bounds__(256) void k_prep(
    const float* __restrict__ x, const float* __restrict__ Wg,
    ushort_t* __restrict__ xb, int* __restrict__ tid, float* __restrict__ tw,
    const float* __restrict__ sg, const float* __restrict__ su,
    const float* __restrict__ sd, const float* __restrict__ wgm,
    const float* __restrict__ wu, const float* __restrict__ wdn,
    ushort_t* __restrict__ Wsh1, ushort_t* __restrict__ Wsd,
    ushort_t* __restrict__ Wgu, ushort_t* __restrict__ Wd) {
  __shared__ float sm[2 * 64 * 65];
  if (blockIdx.x < 512) {
    for (int j = threadIdx.x; j < DIM * NEXP; j += 256)
      sm[(j & 7) * WPAD + (j >> 3)] = Wg[j];
    __syncthreads();
    const int wid = threadIdx.x >> 6, lane = threadIdx.x & 63;
#pragma unroll
    for (int tt2 = 0; tt2 < 4; ++tt2) {
      const int t = blockIdx.x * 16 + wid * 4 + tt2;
      const float* xr = x + (size_t)t * DIM;
      ushort_t* xw = xb + (size_t)t * DIM;
      float acc[NEXP];
#pragma unroll
      for (int e = 0; e < NEXP; ++e) acc[e] = 0.f;
#pragma unroll
      for (int k = 0; k < 4; ++k) {
        const int i = k * 256 + lane * 4;
        const float4 xv = *(const float4*)(xr + i);
        union { ushort_t u[4]; uint2 v; } s;
        s.u[0] = f2bf(xv.x); s.u[1] = f2bf(xv.y);
        s.u[2] = f2bf(xv.z); s.u[3] = f2bf(xv.w);
        *(uint2*)(xw + i) = s.v;
#pragma unroll
        for (int e = 0; e < NEXP; ++e) {
          const float4 wv = *(const float4*)&sm[e * WPAD + i];
          acc[e] += xv.x * wv.x + xv.y * wv.y + xv.z * wv.z + xv.w * wv.w;
        }
      }
#pragma unroll
      for (int e = 0; e < NEXP; ++e) {
        float v = acc[e];
#pragma unroll
        for (int o = 32; o > 0; o >>= 1) v += __shfl_xor(v, o);
        acc[e] = v;
      }
      if (lane == 0) {
        float mx = acc[0];
#pragma unroll
        for (int e = 1; e < NEXP; ++e) mx = fmaxf(mx, acc[e]);
        float p[NEXP]; float s = 0.f;
#pragma unroll
        for (int e = 0; e < NEXP; ++e) { p[e] = __expf(acc[e] - mx); s += p[e]; }
        const float inv = 1.f / s;
#pragma unroll
        for (int e = 0; e < NEXP; ++e) p[e] *= inv;
        int i1 = 0; float s1 = p[0];
#pragma unroll
        for (int e = 1; e < NEXP; ++e) if (p[e] > s1) { s1 = p[e]; i1 = e; }
        int i2 = -1; float s2 = -1.f;
#pragma unroll
        for (int e = 0; e < NEXP; ++e) if (e != i1 && p[e] > s2) { s2 = p[e]; i2 = e; }
        tid[t * 2] = i1; tid[t * 2 + 1] = i2;
        tw[t * 2] = s1;  tw[t * 2 + 1] = s2;
      }
    }
    return;
  }
  int b = blockIdx.x - 512;
  const float *s0, *s1; ushort_t* dst; int R, C; bool ilv;
  int r0, c0;
  if (b < 128) {
    ilv = true; s0 = sg; s1 = su; dst = Wsh1; R = 1024; C = 512;
    c0 = (b & 7) * 64; r0 = (b >> 3) * 64;
  } else if (b < 640) {
    b -= 128; const int e = b >> 6; b &= 63;
    ilv = true;
    s0 = wgm + (size_t)e * 1024 * 256; s1 = wu + (size_t)e * 1024 * 256;
    dst = Wgu + (size_t)e * 512 * 1024; R = 1024; C = 256;
    c0 = (b & 3) * 64; r0 = (b >> 2) * 64;
  } else if (b < 704) {
    b -= 640; ilv = false; s0 = sd; s1 = sd; dst = Wsd; R = 512; C = 1024;
    c0 = (b & 7) * 128; r0 = (b >> 3) * 64;
  } else {
    b -= 704; const int e = b >> 5; b &= 31;
    ilv = false;
    s0 = wdn + (size_t)e * 256 * 1024; s1 = s0;
    dst = Wd + (size_t)e * 1024 * 256; R = 256; C = 1024;
    c0 = (b & 7) * 128; r0 = (b >> 3) * 64;
  }
  const int row16 = threadIdx.x >> 4;
  const int q16   = threadIdx.x & 15;
#pragma unroll
  for (int p = 0; p < 2; ++p) {
    const float* s = p ? s1 : s0;
    const int cc = ilv ? c0 : (c0 + p * 64);
    float (*tt)[65] = (float(*)[65])(sm + p * 64 * 65);
#pragma unroll
    for (int i = 0; i < 64; i += 16) {
      const float4 v = *(const float4*)&s[(size_t)(r0 + row16 + i) * C + cc + q16 * 4];
      tt[q16 * 4 + 0][row16 + i] = v.x;
      tt[q16 * 4 + 1][row16 + i] = v.y;
      tt[q16 * 4 + 2][row16 + i] = v.z;
      tt[q16 * 4 + 3][row16 + i] = v.w;
    }
  }
  __syncthreads();
#pragma unroll
  for (int p = 0; p < 2; ++p) {
    const int cc = ilv ? c0 : (c0 + p * 64);
    float (*tt)[65] = (float(*)[65])(sm + p * 64 * 65);
#pragma unroll
    for (int i = 0; i < 64; i += 16) {
      const int n = cc + row16 + i;
      const int drow = ilv ? (2 * n + p) : n;
      const float4 v = *(const float4*)&tt[row16 + i][q16 * 4];
      union { ushort_t u[4]; uint2 w; } s4;
      s4.u[0] = f2bf(v.x); s4.u[1] = f2bf(v.y);
      s4.u[2] = f2bf(v.z); s4.u[3] = f2bf(v.w);
      *(uint2*)&dst[(size_t)drow * R + r0 + q16 * 4] = s4.w;
    }
  }
}

// ---------------- histogram + prefix ----------------
__global__ __launch_bounds__(1024) void k_scan(const int* __restrict__ tid,
                                               int* __restrict__ cnt,
                                               int* __restrict__ off,
                                               int* __restrict__ cnt2) {
  __shared__ int h[NEXP];
  if (threadIdx.x < NEXP) h[threadIdx.x] = 0;
  __syncthreads();
  int loc[NEXP];
#pragma unroll
  for (int e = 0; e < NEXP; ++e) loc[e] = 0;
  const int4* t4 = (const int4*)tid;
#pragma unroll
  for (int k = 0; k < TOK * TOPK / 4 / 1024; ++k) {
    const int4 v = t4[threadIdx.x + k * 1024];
#pragma unroll
    for (int e = 0; e < NEXP; ++e)
      loc[e] += (v.x == e) + (v.y == e) + (v.z == e) + (v.w == e);
  }
#pragma unroll
  for (int e = 0; e < NEXP; ++e) if (loc[e]) atomicAdd(&h[e], loc[e]);
  __syncthreads();
  if (threadIdx.x == 0) {
    int run = 0;
    for (int e = 0; e < NEXP; ++e) { off[e] = run; cnt[e] = h[e]; run += h[e]; }
  }
  if (threadIdx.x < NEXP) cnt2[threadIdx.x] = 0;
}

// ---------------- ballot-ranked scatter ----------------
__global__ __launch_bounds__(256) void k_scatter(const int* __restrict__ tid,
                                                 const float* __restrict__ tw,
                                                 const int* __restrict__ off,
                                                 int* __restrict__ cnt2,
                                                 int* __restrict__ tok,
                                                 float* __restrict__ wgt,
                                                 int* __restrict__ dstrow) {
  const int t = blockIdx.x * 256 + threadIdx.x;
  const int lane = threadIdx.x & 63;
#pragma unroll
  for (int j = 0; j < TOPK; ++j) {
    const int e = tid[t * 2 + j];
    const float w = tw[t * 2 + j];
    int slot = 0;
#pragma unroll
    for (int ee = 0; ee < NEXP; ++ee) {
      const unsigned long long m = __ballot(e == ee);
      if (m) {
        const int r = __popcll(m & ((1ull << lane) - 1ull));
        const int leader = __ffsll((unsigned long long)m) - 1;
        int base = 0;
        if (lane == leader) base = atomicAdd(&cnt2[ee], (int)__popcll(m));
        base = __shfl(base, leader);
        if (e == ee) slot = off[ee] + base + r;
      }
    }
    tok[slot] = t;
    wgt[slot] = w;
    dstrow[slot] = t * 2 + j;
  }
}

// ---------------- GEMM1 (merged routed+shared): 128x128xBK64, dbuf (r13) ----
__global__ __launch_bounds__(256) void k_gemm1(
    const ushort_t* __restrict__ A0, const ushort_t* __restrict__ Bgu,
    const ushort_t* __restrict__ Bsh,
    ushort_t* __restrict__ he, ushort_t* __restrict__ hs,
    const int* __restrict__ tok,
    const int* __restrict__ cnt, const int* __restrict__ off) {
  constexpr int K = 1024, NB = 4, NGROUP = 16, MBSLOT = 16;
  constexpr int NWG = NGROUP * MBSLOT * NB;
  __shared__ __attribute__((aligned(16))) ushort_t lA[2][128 * 64];
  __shared__ __attribute__((aligned(16))) ushort_t lB[2][128 * 64];

  const int wg = (blockIdx.x % 8) * (NWG / 8) + blockIdx.x / 8;
  const int g = wg / (MBSLOT * NB);
  const int rem = wg % (MBSLOT * NB);
  const int mbslot = rem / NB;
  const int nb = rem % NB;
  const int nBase = nb * 128;

  int m_e, offE = 0, rowq = 0, hh = 0;
  bool gat = false;
  const ushort_t* Abase = A0;
  const ushort_t* Bblk;
  if (g < 8) {
    gat = true; m_e = cnt[g]; offE = off[g];
    Bblk = Bgu + (size_t)g * 512 * 1024;
  } else {
    const int q = (g - 8) >> 1; hh = (g - 8) & 1;
    rowq = q * 2048; m_e = 2048;
    Abase = A0 + (size_t)rowq * 1024;
    Bblk = Bsh + (size_t)hh * 512 * 1024;
  }
  if (m_e == 0) return;

  const int wid = threadIdx.x >> 6, lane = threadIdx.x & 63;
  const int wm = wid >> 1, wn = wid & 1;
  const int l15 = lane & 15, lq = lane >> 4;

  const ushort_t* bptr[4];
#pragma unroll
  for (int cc = 0; cc < 4; ++cc) {
    const int c = wid * 4 + cc;
    const int rl = c * 8 + (lane >> 3);
    const int slot = (lane & 7) ^ (rl & 7);
    bptr[cc] = Bblk + (size_t)(nBase + rl) * K + slot * 8;
  }

  for (int mb = mbslot; mb * 128 < m_e; mb += MBSLOT) {
    const int mBase = mb * 128;
    const ushort_t* aptr[4];
#pragma unroll
    for (int cc = 0; cc < 4; ++cc) {
      const int c = wid * 4 + cc;
      const int rl = c * 8 + (lane >> 3);
      const int slot = (lane & 7) ^ (rl & 7);
      const int gr = mBase + rl;
      const int gc = (gr < m_e) ? gr : (m_e - 1);
      const ushort_t* ar;
      if (gat) ar = A0 + (size_t)tok[offE + gc] * 1024;
      else     ar = Abase + (size_t)gc * K;
      aptr[cc] = ar + slot * 8;
    }

    auto stage = [&](int buf, int ktv) {
#pragma unroll
      for (int cc = 0; cc < 4; ++cc) {
        const int c = wid * 4 + cc;
        gload_lds16(aptr[cc] + ktv, &lA[buf][c * 512]);
        gload_lds16(bptr[cc] + ktv, &lB[buf][c * 512]);
      }
    };

    f32x4 acc[4][4];
#pragma unroll
    for (int mi = 0; mi < 4; ++mi)
#pragma unroll
      for (int ni = 0; ni < 4; ++ni) acc[mi][ni] = (f32x4){0.f, 0.f, 0.f, 0.f};

    stage(0, 0);
    int cur = 0;
    for (int kt = 0; kt < K; kt += 64) {
      if (kt + 64 < K) {
        stage(cur ^ 1, kt + 64);
        asm volatile("s_waitcnt vmcnt(8)" ::: "memory");
      } else {
        asm volatile("s_waitcnt vmcnt(0)" ::: "memory");
      }
      __builtin_amdgcn_s_barrier();
#pragma unroll
      for (int kk = 0; kk < 2; ++kk) {
        bf16x8 af[4], bfr[4];
#pragma unroll
        for (int mi = 0; mi < 4; ++mi) {
          const int row = wm * 64 + mi * 16 + l15;
          const int cb = ((kk * 32 + lq * 8) * 2) ^ ((row & 7) << 4);
          af[mi] = *(const bf16x8*)((const char*)lA + cur * 16384 + row * 128 + cb);
        }
#pragma unroll
        for (int ni = 0; ni < 4; ++ni) {
          const int row = wn * 64 + ni * 16 + l15;
          const int cb = ((kk * 32 + lq * 8) * 2) ^ ((row & 7) << 4);
          bfr[ni] = *(const bf16x8*)((const char*)lB + cur * 16384 + row * 128 + cb);
        }
#pragma unroll
        for (int mi = 0; mi < 4; ++mi)
#pragma unroll
          for (int ni = 0; ni < 4; ++ni)
            acc[mi][ni] = __builtin_amdgcn_mfma_f32_16x16x32_bf16(
                af[mi], bfr[ni], acc[mi][ni], 0, 0, 0);
      }
      __builtin_amdgcn_s_barrier();
      cur ^= 1;
    }

#pragma unroll
    for (int mi = 0; mi < 4; ++mi) {
#pragma unroll
      for (int r = 0; r < 4; ++r) {
        const int gg = mBase + wm * 64 + mi * 16 + lq * 4 + r;
        const bool ok = gg < m_e;
#pragma unroll
        for (int ni = 0; ni < 4; ++ni) {
          const float v = acc[mi][ni][r];
          const int c = nBase + wn * 64 + ni * 16 + l15;
          const float o = __shfl_xor(v, 1);
          if (!(c & 1) && ok) {
            const float hv = (v / (1.f + __expf(-v))) * o;
            if (gat) he[(size_t)(offE + gg) * 256 + (c >> 1)] = f2bf(hv);
            else     hs[(size_t)(rowq + gg) * 512 + hh * 256 + (c >> 1)] = f2bf(hv);
          }
        }
      }
    }
  }
}

// ---- GEMM2r: routed. B-resident + per-wave private A pipeline, NO barriers --
// 256 blocks x 512 thr. bid&7 = expert(=XCD). c0=bid>>3: nb=c0&7 (128-col
// strip), mslot=c0>>3 (4). Wave tile 32m x 128n; wave-private lA dbuf 2x4KB.
__global__ __launch_bounds__(512, 1) void k_gemm2r(
    const ushort_t* __restrict__ he, const ushort_t* __restrict__ Wd,
    ushort_t* __restrict__ contrib, const float* __restrict__ wgt,
    const int* __restrict__ cnt, const int* __restrict__ off,
    const int* __restrict__ dstrow) {
  constexpr int K = 256;
  __shared__ __attribute__((aligned(16))) ushort_t lB[128 * 256];     // 64KB
  __shared__ __attribute__((aligned(16))) ushort_t lA[8][2][32 * 64]; // 64KB

  const int e = blockIdx.x & 7;
  const int c0 = blockIdx.x >> 3;
  const int nb = c0 & 7;
  const int mslot = c0 >> 3;
  const int nBase = nb * 128;

  const int m_e = cnt[e];
  const int offE = (m_e > 0) ? off[e] : 0;
  const ushort_t* Abase = he + (size_t)offE * K;
  const ushort_t* Bblk = Wd + (size_t)e * 1024 * K;

  const int wid = threadIdx.x >> 6, lane = threadIdx.x & 63;
  const int l15 = lane & 15, lq = lane >> 4;

  // stage B once: linear slot L=(wid*8+i)*64+lane; row=L>>5, s=L&31; src slot
  // = s ^ (row&31) so reads at ck^(row&31) hit <=2-way banks.
  if (m_e > 0) {
#pragma unroll
    for (int i = 0; i < 8; ++i) {
      const int L = (wid * 8 + i) * 64 + lane;
      const int row = L >> 5, s = L & 31;
      const int ss = s ^ (row & 31);
      gload_lds16(Bblk + (size_t)(nBase + row) * K + ss * 8,
                  ((char*)lB) + (size_t)(wid * 8 + i) * 1024);
    }
  }

  char* lAw = (char*)&lA[wid][0][0];
  auto stageA = [&](int buf, int chunk, int kc) {
#pragma unroll
    for (int i = 0; i < 4; ++i) {
      const int L = i * 64 + lane;
      const int row = L >> 3, s = L & 7;
      const int ss = s ^ (row & 7);
      int gr = chunk * 32 + row;
      if (gr >= m_e) gr = m_e - 1;
      gload_lds16(Abase + (size_t)gr * K + kc * 64 + ss * 8,
                  lAw + (size_t)buf * 4096 + (size_t)i * 1024);
    }
  };

  int cw = mslot * 8 + wid;
  bool active = (m_e > 0) && (cw * 32 < m_e);
  if (m_e > 0) stageA(0, active ? cw : 0, 0);
  // my 8 B-loads are the oldest; 4 A-loads newest -> vmcnt(4) retires B.
  asm volatile("s_waitcnt vmcnt(4)" ::: "memory");
  __builtin_amdgcn_s_barrier();
  if (!active) return;

  int buf = 0;
  while (active) {
    f32x4 acc[2][8];
#pragma unroll
    for (int mi = 0; mi < 2; ++mi)
#pragma unroll
      for (int ni = 0; ni < 8; ++ni) acc[mi][ni] = (f32x4){0.f, 0.f, 0.f, 0.f};

    for (int kc = 0; kc < 4; ++kc) {
      int nc = cw, nk = kc + 1;
      if (nk == 4) { nk = 0; nc = cw + 32; }
      if (nc * 32 < m_e) {
        stageA(buf ^ 1, nc, nk);
        asm volatile("s_waitcnt vmcnt(4)" ::: "memory");
      } else {
        asm volatile("s_waitcnt vmcnt(0)" ::: "memory");
      }
      const char* sA = lAw + buf * 4096;
#pragma unroll
      for (int kk = 0; kk < 2; ++kk) {
        bf16x8 af[2], bfr[8];
#pragma unroll
        for (int mi = 0; mi < 2; ++mi) {
          const int row = mi * 16 + l15;
          af[mi] = *(const bf16x8*)(sA + row * 128 + (((kk * 4 + lq) ^ (row & 7)) << 4));
        }
#pragma unroll
        for (int ni = 0; ni < 8; ++ni) {
          const int brow = ni * 16 + l15;
          const int ck = kc * 8 + kk * 4 + lq;
          bfr[ni] = *(const bf16x8*)((const char*)lB + brow * 512 +
                                     ((ck ^ (brow & 31)) << 4));
        }
#pragma unroll
        for (int mi = 0; mi < 2; ++mi)
#pragma unroll
          for (int ni = 0; ni < 8; ++ni)
            acc[mi][ni] = __builtin_amdgcn_mfma_f32_16x16x32_bf16(
                af[mi], bfr[ni], acc[mi][ni], 0, 0, 0);
      }
      buf ^= 1;
    }

    // epilogue: contrib[dstrow] = bf16(v * wgt)
#pragma unroll
    for (int mi = 0; mi < 2; ++mi) {
#pragma unroll
      for (int r = 0; r < 4; ++r) {
        const int gg = cw * 32 + mi * 16 + lq * 4 + r;
        if (gg < m_e) {
          const float w = wgt[offE + gg];
          const int dr = dstrow[offE + gg];
#pragma unroll
          for (int ni = 0; ni < 8; ++ni) {
            const int c = nBase + ni * 16 + l15;
            contrib[(size_t)dr * 1024 + c] = f2bf(acc[mi][ni][r] * w);
          }
        }
      }
    }
    cw += 32;
    active = cw * 32 < m_e;
  }
  asm volatile("s_waitcnt vmcnt(0)" ::: "memory");
}

// ---- GEMM2s: shared + combine. B-resident + per-wave A pipeline, no barriers
// 256 blocks x 512 thr. wg=(bid&7)*32+bid>>3: nstrip=wg>>4 (16 x 64 cols),
// mslot=wg&15. Wave tile 32m x 64n; chunks stride 128.
__global__ __launch_bounds__(512, 1) void k_gemm2s(
    const ushort_t* __restrict__ hs, const ushort_t* __restrict__ Wsd,
    const ushort_t* __restrict__ contrib, float* __restrict__ out) {
  constexpr int K = 512;
  __shared__ __attribute__((aligned(16))) ushort_t lB[64 * 512];      // 64KB
  __shared__ __attribute__((aligned(16))) ushort_t lA[8][2][32 * 64]; // 64KB

  const int wg = (blockIdx.x & 7) * 32 + (blockIdx.x >> 3);
  const int nstrip = wg >> 4;
  const int mslot = wg & 15;
  const int nBase = nstrip * 64;

  const int wid = threadIdx.x >> 6, lane = threadIdx.x & 63;
  const int l15 = lane & 15, lq = lane >> 4;

  // stage B once: L=(wid*8+i)*64+lane; row=L>>6, s=L&63; src slot = s^row.
#pragma unroll
  for (int i = 0; i < 8; ++i) {
    const int L = (wid * 8 + i) * 64 + lane;
    const int row = L >> 6, s = L & 63;
    const int ss = s ^ row;
    gload_lds16(Wsd + (size_t)(nBase + row) * K + ss * 8,
                ((char*)lB) + (size_t)(wid * 8 + i) * 1024);
  }

  char* lAw = (char*)&lA[wid][0][0];
  auto stageA = [&](int buf, int chunk, int kc) {
#pragma unroll
    for (int i = 0; i < 4; ++i) {
      const int L = i * 64 + lane;
      const int row = L >> 3, s = L & 7;
      const int ss = s ^ (row & 7);
      gload_lds16(hs + (size_t)(chunk * 32 + row) * K + kc * 64 + ss * 8,
                  lAw + (size_t)buf * 4096 + (size_t)i * 1024);
    }
  };

  int cw = mslot * 8 + wid;          // 0..127, chunks of 32 rows, stride 128
  stageA(0, cw, 0);
  asm volatile("s_waitcnt vmcnt(4)" ::: "memory");   // retire my 8 B-loads
  __builtin_amdgcn_s_barrier();

  int buf = 0;
  for (int rep = 0; rep < 2; ++rep) {                // 256 chunks / 128 waves
    f32x4 acc[2][4];
#pragma unroll
    for (int mi = 0; mi < 2; ++mi)
#pragma unroll
      for (int ni = 0; ni < 4; ++ni) acc[mi][ni] = (f32x4){0.f, 0.f, 0.f, 0.f};

    for (int kc = 0; kc < 8; ++kc) {
      int nc = cw, nk = kc + 1;
      if (nk == 8) { nk = 0; nc = cw + 128; }
      if (nc < 256) {
        stageA(buf ^ 1, nc, nk);
        asm volatile("s_waitcnt vmcnt(4)" ::: "memory");
      } else {
        asm volatile("s_waitcnt vmcnt(0)" ::: "memory");
      }
      const char* sA = lAw + buf * 4096;
#pragma unroll
      for (int kk = 0; kk < 2; ++kk) {
        bf16x8 af[2], bfr[4];
#pragma unroll
        for (int mi = 0; mi < 2; ++mi) {
          const int row = mi * 16 + l15;
          af[mi] = *(const bf16x8*)(sA + row * 128 + (((kk * 4 + lq) ^ (row & 7)) << 4));
        }
#pragma unroll
        for (int ni = 0; ni < 4; ++ni) {
          const int brow = ni * 16 + l15;
          const int ck = kc * 8 + kk * 4 + lq;
          bfr[ni] = *(const bf16x8*)((const char*)lB + brow * 1024 +
                                     ((ck ^ brow) << 4));
        }
#pragma unroll
        for (int mi = 0; mi < 2; ++mi)
#pragma unroll
          for (int ni = 0; ni < 4; ++ni)
            acc[mi][ni] = __builtin_amdgcn_mfma_f32_16x16x32_bf16(
                af[mi], bfr[ni], acc[mi][ni], 0, 0, 0);
      }
      buf ^= 1;
    }

    // epilogue: out = v + contrib[t*2] + contrib[t*2+1]
#pragma unroll
    for (int mi = 0; mi < 2; ++mi) {
#pragma unroll
      for (int r = 0; r < 4; ++r) {
        const int gg = cw * 32 + mi * 16 + lq * 4 + r;
#pragma unroll
        for (int ni = 0; ni < 4; ++ni) {
          const int c = nBase + ni * 16 + l15;
          out[(size_t)gg * 1024 + c] = acc[mi][ni][r]
              + bf2f(contrib[(size_t)(gg * 2) * 1024 + c])
              + bf2f(contrib[(size_t)(gg * 2 + 1) * 1024 + c]);
        }
      }
    }
    cw += 128;
  }
  asm volatile("s_waitcnt vmcnt(0)" ::: "memory");
}

// ---------------- launch ----------------
extern "C" void kernel_launch(void* const* d_in, const int* in_sizes, int n_in,
                              void* d_out, int out_size, void* d_ws, size_t ws_size,
                              hipStream_t stream) {
  (void)in_sizes; (void)n_in; (void)out_size; (void)ws_size;
  const float* x      = (const float*)d_in[0];
  const float* Wg     = (const float*)d_in[1];
  const float* w_gate = (const float*)d_in[2];
  const float* w_up   = (const float*)d_in[3];
  const float* w_down = (const float*)d_in[4];
  const float* sg     = (const float*)d_in[5];
  const float* su     = (const float*)d_in[6];
  const float* sd     = (const float*)d_in[7];
  float* out = (float*)d_out;

  char* ws = (char*)d_ws;
  size_t o = 0;
  ushort_t* xb    = (ushort_t*)(ws + o); o += (size_t)TOK * DIM * 2;
  ushort_t* Wsh1  = (ushort_t*)(ws + o); o += (size_t)1024 * 1024 * 2;
  ushort_t* Wsd   = (ushort_t*)(ws + o); o += (size_t)1024 * 512 * 2;
  ushort_t* Wgu   = (ushort_t*)(ws + o); o += (size_t)NEXP * 512 * 1024 * 2;
  ushort_t* Wd    = (ushort_t*)(ws + o); o += (size_t)NEXP * 1024 * 256 * 2;
  ushort_t* hs    = (ushort_t*)(ws + o); o += (size_t)TOK * 512 * 2;
  ushort_t* he    = (ushort_t*)(ws + o); o += (size_t)TOK * TOPK * 256 * 2;
  int*   tid   = (int*)(ws + o);   o += (size_t)TOK * TOPK * 4;
  float* tw    = (float*)(ws + o); o += (size_t)TOK * TOPK * 4;
  int*   tok   = (int*)(ws + o);   o += (size_t)TOK * TOPK * 4;
  float* wgt   = (float*)(ws + o); o += (size_t)TOK * TOPK * 4;
  int*   dstrow= (int*)(ws + o);   o += (size_t)TOK * TOPK * 4;
  int*   cnt   = (int*)(ws + o);   o += 64;
  int*   offp  = (int*)(ws + o);   o += 64;
  int*   cnt2  = (int*)(ws + o);   o += 64;
  ushort_t* contrib = (ushort_t*)(ws + o);  // [TOK*2][1024] bf16, token-major

  k_prep<<<1472, 256, 0, stream>>>(x, Wg, xb, tid, tw, sg, su, sd,
                                   w_gate, w_up, w_down, Wsh1, Wsd, Wgu, Wd);
  k_scan<<<1, 1024, 0, stream>>>(tid, cnt, offp, cnt2);
  k_scatter<<<TOK / 256, 256, 0, stream>>>(tid, tw, offp, cnt2, tok, wgt, dstrow);

  // merged GEMM1 (routed gathered + shared), 1024 blocks x 256 thr
  k_gemm1<<<1024, 256, 0, stream>>>(xb, Wgu, Wsh1, he, hs, tok, cnt, offp);
  // routed GEMM2 -> token-major bf16 contrib (barrier-free wave pipeline)
  k_gemm2r<<<256, 512, 0, stream>>>(he, Wd, contrib, wgt, cnt, offp, dstrow);
  // shared GEMM2 + combine -> out (barrier-free wave pipeline)
  k_gemm2s<<<256, 512, 0, stream>>>(hs, Wsd, contrib, out);
}